// Round 7
// baseline (212.962 us; speedup 1.0000x reference)
//
#include <hip/hip_runtime.h>
#include <hip/hip_bf16.h>
#include <math.h>

// LoRA attention, MI355X bf16-MFMA pipeline, round 7.
// 128x128x64 GEMM, 256 threads / 4 waves (each 64x64 out: 16 frags, fat MFMA
// clusters), 64 KiB LDS -> 2 independent blocks/CU (cross-block bubble fill).
// 2 phases/K-tile; stage leads: A (streamed) 3 phases, B (L2-resident) 1 phase.
// Scores fuses exp + row-sum (no softmax kernel); PV normalizes in epilogue.

typedef __attribute__((ext_vector_type(4))) float f32x4;
typedef __attribute__((ext_vector_type(8))) short bf8;   // 8 x bf16
typedef __attribute__((ext_vector_type(4))) short bf4;   // 4 x bf16

__device__ __forceinline__ float bf2f(unsigned short b) {
  union { unsigned u; float f; } c; c.u = ((unsigned)b) << 16; return c.f;
}
__device__ __forceinline__ unsigned short f2bf(float f) {
  union { float f; unsigned u; } c; c.f = f;
  return (unsigned short)((c.u + 0x7fffu + ((c.u >> 16) & 1u)) >> 16);
}
__device__ __forceinline__ void gload16(const void* g, void* l) {
  __builtin_amdgcn_global_load_lds((const __attribute__((address_space(1))) void*)g,
                                   (__attribute__((address_space(3))) void*)l, 16, 0, 0);
}

// ---------------- cast fp32 -> bf16 ----------------
__global__ __launch_bounds__(256)
void k_cast(const float* __restrict__ x, __hip_bfloat16* __restrict__ o) {
  long i = ((long)blockIdx.x * 256 + threadIdx.x) * 8;
  float4 a = *(const float4*)&x[i];
  float4 b = *(const float4*)&x[i + 4];
  union { bf8 v; unsigned short h[8]; } u;
  u.h[0] = f2bf(a.x); u.h[1] = f2bf(a.y); u.h[2] = f2bf(a.z); u.h[3] = f2bf(a.w);
  u.h[4] = f2bf(b.x); u.h[5] = f2bf(b.y); u.h[6] = f2bf(b.z); u.h[7] = f2bf(b.w);
  *(bf8*)&o[i] = u.v;
}

// ---------------- Weff = W + B@A, concat [2304][768] bf16, + bias concat ----------------
__global__ __launch_bounds__(256)
void k_fold3(const float* __restrict__ W0, const float* __restrict__ A0, const float* __restrict__ B0,
             const float* __restrict__ W1, const float* __restrict__ A1, const float* __restrict__ B1,
             const float* __restrict__ W2, const float* __restrict__ A2, const float* __restrict__ B2,
             const float* __restrict__ bq, const float* __restrict__ bk, const float* __restrict__ bv,
             __hip_bfloat16* __restrict__ out, float* __restrict__ bcat) {
  int idx = blockIdx.x * 256 + threadIdx.x;
  if (idx < 2304)
    bcat[idx] = (idx < 768) ? bq[idx] : (idx < 1536) ? bk[idx - 768] : bv[idx - 1536];
  int t = idx / 589824, j = idx - t * 589824;
  const float* W = (t == 0) ? W0 : (t == 1) ? W1 : W2;
  const float* A = (t == 0) ? A0 : (t == 1) ? A1 : A2;
  const float* Bl = (t == 0) ? B0 : (t == 1) ? B1 : B2;
  int d = j % 768, o = j / 768;
  float acc = W[j];
  #pragma unroll
  for (int r = 0; r < 32; ++r) acc += Bl[o * 32 + r] * A[r * 768 + d];
  out[idx] = __float2bfloat16(acc);
}

// ---------------- 128x128x64 4-wave GEMM, 2 blocks/CU ----------------
// Out[m][n] = sum_k A[m][k] * B[n][k]
// MODE 0: PV   (A=P' ld4096, B=Vt ld8192 +z*4096, fp32 out / lsum)
// MODE 1: scores (A=Q ld1536, B=A+768; out P'=exp(acc*scale) bf16 ld4096 + atomic lsum)
// MODE 3: proj (col<1536 -> bf16 [8192][1536] +bias; else Vt [768][8192] +bias)
// Waves 2x2, each 64x64 out (4x4 frags). Phases per K-tile:
//   P0: read af all (8 b128) + bv lo (4); stage B(t+1)->buf d^1; bar; 16 MFMA; bar
//   P1: read bv hi (4);                  stage A(t+2)->buf d;   bar; 16 MFMA; vmcnt(4); bar
template<int MODE>
__global__ __launch_bounds__(256, 2)
void k_g4(const __hip_bfloat16* __restrict__ Ag, const __hip_bfloat16* __restrict__ Bg,
          const float* __restrict__ bias, void* __restrict__ Og, void* __restrict__ Og2,
          float* __restrict__ lsum, float scale)
{
  __shared__ short lds[32768];   // 64 KiB: [buf2][opA/B][128 rows x 64 k bf16]
  constexpr int NT = (MODE == 0) ? 64 : 12;
  const int tid = threadIdx.x, w = tid >> 6, lane = tid & 63;
  const int wm = w >> 1, wn = w & 1;
  const int lnlo = lane & 15, lnhi = lane >> 4;

  // T1 XCD swizzle, N-fast tile mapping
  const int gy = gridDim.y;
  const int nwg = gridDim.x * gy;
  const int w0 = blockIdx.y * gridDim.x + blockIdx.x;
  const int wid = (w0 & 7) * (nwg >> 3) + (w0 >> 3);
  const long M0 = (long)(wid / gy) * 128;
  const long N0 = (long)(wid % gy) * 128;

  const __hip_bfloat16 *A, *B; long lda, ldb;
  if constexpr (MODE == 0) {
    A = Ag + (long)blockIdx.z * 4096 * 4096; lda = 4096;
    B = Bg + (long)blockIdx.z * 4096;        ldb = 8192;
  } else if constexpr (MODE == 1) {
    A = Ag + (long)blockIdx.z * 4096 * 1536; B = A + 768; lda = 1536; ldb = 1536;
  } else {
    A = Ag; B = Bg; lda = 768; ldb = 768;
  }

  // staging: half-tile 64 rows x 64 k; 256 thr -> 2 gload16 per half (rows +0/+32).
  // source col pre-swizzled (T2 inverse), LDS dest linear.
  const int srow = tid >> 3;                       // 0..31
  const int scol = (((tid & 7) ^ (srow & 7)) << 3);
  const __hip_bfloat16* pA[2] = { A + (M0 + srow) * lda + scol, A + (M0 + 64 + srow) * lda + scol };
  const __hip_bfloat16* pB[2] = { B + (N0 + srow) * ldb + scol, B + (N0 + 64 + srow) * ldb + scol };
  char* Lc = (char*)lds;
  auto slot = [&](int op, int h, int d) { return Lc + d * 32768 + op * 16384 + h * 8192; };
  auto rd = [&](const char* base, int row, int k) -> bf8 {   // T2-swizzled read
    const int sb = ((k << 6) + (lnhi << 4)) ^ ((row & 7) << 4);
    return *(const bf8*)(base + row * 128 + sb);
  };

  // stage one operand's full K-tile (both 64-row halves, 4 gloads)
  auto stageA = [&](int koff, int d) {
    #pragma unroll
    for (int h = 0; h < 2; ++h) {
      char* s = slot(0, h, d) + w * 1024;
      gload16(pA[h] + koff, s);
      gload16(pA[h] + koff + 32 * lda, s + 4096);
    }
  };
  auto stageB = [&](int koff, int d) {
    #pragma unroll
    for (int h = 0; h < 2; ++h) {
      char* s = slot(1, h, d) + w * 1024;
      gload16(pB[h] + koff, s);
      gload16(pB[h] + koff + 32 * ldb, s + 4096);
    }
  };

  f32x4 acc[4][4] = {};   // [mi][ni]
  bf8 af[4][2], bv[2][2];

  // prologue: [B0][A0][B1][A1] -> vmcnt(8) retires tile0
  stageB(0, 0); stageA(0, 0); stageB(64, 1); stageA(64, 1);
  asm volatile("s_waitcnt vmcnt(8)" ::: "memory");
  __builtin_amdgcn_s_barrier();
  asm volatile("" ::: "memory");

  for (int t = 0; t < NT; ++t) {
    const int d = t & 1, dx = d ^ 1;
    const int tb = ((t + 1 < NT) ? t + 1 : NT - 1) * 64;   // clamp: benign restage
    const int ta = ((t + 2 < NT) ? t + 2 : NT - 1) * 64;
    const char* Ab = Lc + d * 32768;
    const char* Bb = Ab + 16384;

    // ---- P0: af all m-frags + bv n0-1; stage B(t+1) -> buf dx ----
    #pragma unroll
    for (int mi = 0; mi < 4; ++mi)
      #pragma unroll
      for (int k = 0; k < 2; ++k) af[mi][k] = rd(Ab, wm * 64 + mi * 16 + lnlo, k);
    #pragma unroll
    for (int ni = 0; ni < 2; ++ni)
      #pragma unroll
      for (int k = 0; k < 2; ++k) bv[ni][k] = rd(Bb, wn * 64 + ni * 16 + lnlo, k);
    stageB(tb, dx);
    asm volatile("" ::: "memory");
    __builtin_amdgcn_s_barrier();
    __builtin_amdgcn_s_setprio(1);
    #pragma unroll
    for (int mi = 0; mi < 4; ++mi)
      #pragma unroll
      for (int ni = 0; ni < 2; ++ni) {
        acc[mi][ni] = __builtin_amdgcn_mfma_f32_16x16x32_bf16(af[mi][0], bv[ni][0], acc[mi][ni], 0,0,0);
        acc[mi][ni] = __builtin_amdgcn_mfma_f32_16x16x32_bf16(af[mi][1], bv[ni][1], acc[mi][ni], 0,0,0);
      }
    __builtin_amdgcn_s_setprio(0);
    __builtin_amdgcn_s_barrier();
    asm volatile("" ::: "memory");

    // ---- P1: bv n2-3 (af reused); stage A(t+2) -> buf d ----
    #pragma unroll
    for (int ni = 0; ni < 2; ++ni)
      #pragma unroll
      for (int k = 0; k < 2; ++k) bv[ni][k] = rd(Bb, wn * 64 + 32 + ni * 16 + lnlo, k);
    stageA(ta, d);
    asm volatile("" ::: "memory");
    __builtin_amdgcn_s_barrier();
    __builtin_amdgcn_s_setprio(1);
    #pragma unroll
    for (int mi = 0; mi < 4; ++mi)
      #pragma unroll
      for (int ni = 0; ni < 2; ++ni) {
        acc[mi][2+ni] = __builtin_amdgcn_mfma_f32_16x16x32_bf16(af[mi][0], bv[ni][0], acc[mi][2+ni], 0,0,0);
        acc[mi][2+ni] = __builtin_amdgcn_mfma_f32_16x16x32_bf16(af[mi][1], bv[ni][1], acc[mi][2+ni], 0,0,0);
      }
    __builtin_amdgcn_s_setprio(0);
    asm volatile("s_waitcnt vmcnt(4)" ::: "memory");   // retires tile t+1 (A&B)
    __builtin_amdgcn_s_barrier();
    asm volatile("" ::: "memory");
  }

  // epilogue: C/D map col=lane&15, row=(lane>>4)*4+r
  #pragma unroll
  for (int mi = 0; mi < 4; ++mi) {
    const long row = M0 + wm * 64 + mi * 16 + lnhi * 4;
    if constexpr (MODE == 0) {
      float* Of = (float*)Og + (long)blockIdx.z * 4096 * 768;
      const float* lz = lsum + (long)blockIdx.z * 4096;
      float linv[4];
      #pragma unroll
      for (int r = 0; r < 4; ++r) linv[r] = 1.0f / lz[row + r];
      #pragma unroll
      for (int ni = 0; ni < 4; ++ni) {
        const long col = N0 + wn * 64 + ni * 16 + lnlo;
        #pragma unroll
        for (int r = 0; r < 4; ++r) Of[(row + r) * 768 + col] = acc[mi][ni][r] * linv[r];
      }
    } else if constexpr (MODE == 1) {
      __hip_bfloat16* Ob = (__hip_bfloat16*)Og + (long)blockIdx.z * 4096 * 4096;
      float* lz = lsum + (long)blockIdx.z * 4096;
      float rs[4] = {0.f, 0.f, 0.f, 0.f};
      #pragma unroll
      for (int ni = 0; ni < 4; ++ni) {
        const long col = N0 + wn * 64 + ni * 16 + lnlo;
        #pragma unroll
        for (int r = 0; r < 4; ++r) {
          const float e = __expf(fminf(acc[mi][ni][r] * scale, 70.0f));
          rs[r] += e;
          *(unsigned short*)&Ob[(row + r) * 4096 + col] = f2bf(e);
        }
      }
      #pragma unroll
      for (int r = 0; r < 4; ++r) {
        float v = rs[r];
        v += __shfl_xor(v, 1); v += __shfl_xor(v, 2);
        v += __shfl_xor(v, 4); v += __shfl_xor(v, 8);
        if (lnlo == 0) atomicAdd(&lz[row + r], v);
      }
    } else {
      #pragma unroll
      for (int ni = 0; ni < 4; ++ni) {
        const long col = N0 + wn * 64 + ni * 16 + lnlo;
        const float bvl = bias[col];
        if (col < 1536) {
          __hip_bfloat16* O = (__hip_bfloat16*)Og;
          #pragma unroll
          for (int r = 0; r < 4; ++r)
            *(unsigned short*)&O[(row + r) * 1536 + col] = f2bf(acc[mi][ni][r] + bvl);
        } else {
          __hip_bfloat16* O2 = (__hip_bfloat16*)Og2;
          bf4 v;
          #pragma unroll
          for (int r = 0; r < 4; ++r) v[r] = (short)f2bf(acc[mi][ni][r] + bvl);
          *(bf4*)&O2[(col - 1536) * 8192 + row] = v;
        }
      }
    }
  }
}

extern "C" void kernel_launch(void* const* d_in, const int* in_sizes, int n_in,
                              void* d_out, int out_size, void* d_ws, size_t ws_size,
                              hipStream_t stream) {
  const float* x  = (const float*)d_in[0];
  const float* Wq = (const float*)d_in[1]; const float* bq = (const float*)d_in[2];
  const float* Wk = (const float*)d_in[3]; const float* bk = (const float*)d_in[4];
  const float* Wv = (const float*)d_in[5]; const float* bv = (const float*)d_in[6];
  const float* Aq = (const float*)d_in[7]; const float* Bq = (const float*)d_in[8];
  const float* Ak = (const float*)d_in[9]; const float* Bk = (const float*)d_in[10];
  const float* Av = (const float*)d_in[11]; const float* Bv = (const float*)d_in[12];

  // ws layout (bf16 elems), ~121 MB
  __hip_bfloat16* Xb   = (__hip_bfloat16*)d_ws;        // [8192][768]
  __hip_bfloat16* WeA  = Xb  + 6291456;                // [2304][768]
  __hip_bfloat16* QKb  = WeA + 1769472;                // [8192][1536] (Q 0-767, K 768-1535)
  __hip_bfloat16* Vt   = QKb + 12582912;               // [768][8192]
  __hip_bfloat16* Pb   = Vt  + 6291456;                // [2][4096][4096] unnormalized exp
  float*          bcat = (float*)(Pb + 33554432);      // [2304]
  float*          lsum = bcat + 2304;                  // [2][4096] row sums
  float* out = (float*)d_out;

  k_cast<<<3072, 256, 0, stream>>>(x, Xb);
  k_fold3<<<6912, 256, 0, stream>>>(Wq, Aq, Bq, Wk, Ak, Bk, Wv, Av, Bv,
                                    bq, bk, bv, WeA, bcat);
  hipMemsetAsync(lsum, 0, 8192 * sizeof(float), stream);

  // projections: M=8192, N=2304, K=768
  k_g4<3><<<dim3(64, 18, 1), 256, 0, stream>>>(Xb, WeA, bcat, QKb, Vt, nullptr, 1.0f);
  // scores + exp + rowsum: per batch M=N=4096, K=768
  const float sc = 0.036084391824351615f;
  k_g4<1><<<dim3(32, 32, 2), 256, 0, stream>>>(QKb, nullptr, nullptr, Pb, nullptr, lsum, sc);
  // PV: per batch M=4096, N=768, K=4096; epilogue normalizes by lsum
  k_g4<0><<<dim3(32, 6, 2), 256, 0, stream>>>(Pb, Vt, nullptr, out, nullptr, lsum, 1.0f);
}

// Round 8
// 207.833 us; speedup vs baseline: 1.0247x; 1.0247x over previous
//
#include <hip/hip_runtime.h>
#include <hip/hip_bf16.h>
#include <math.h>

// LoRA attention, MI355X bf16-MFMA pipeline, round 8.
// One 128x128x64 GEMM template: 8 waves (2Mx4N), 64 KiB LDS -> 2 blk/CU
// (4 waves/SIMD), race-free 4-phase/2-K-step stage ledger, counted vmcnt(2),
// and N-MARCHING: each block computes MARCH n-tiles with one pipeline
// (prologue amortized, per-tile epilogue overlapped with next tile's staging).
// Scores fuses exp + atomic row-sum; PV normalizes in epilogue.

typedef __attribute__((ext_vector_type(4))) float f32x4;
typedef __attribute__((ext_vector_type(8))) short bf8;   // 8 x bf16
typedef __attribute__((ext_vector_type(4))) short bf4;   // 4 x bf16

__device__ __forceinline__ float bf2f(unsigned short b) {
  union { unsigned u; float f; } c; c.u = ((unsigned)b) << 16; return c.f;
}
__device__ __forceinline__ unsigned short f2bf(float f) {
  union { float f; unsigned u; } c; c.f = f;
  return (unsigned short)((c.u + 0x7fffu + ((c.u >> 16) & 1u)) >> 16);
}
__device__ __forceinline__ void gload16(const void* g, void* l) {
  __builtin_amdgcn_global_load_lds((const __attribute__((address_space(1))) void*)g,
                                   (__attribute__((address_space(3))) void*)l, 16, 0, 0);
}

// ---------------- cast fp32 -> bf16 ----------------
__global__ __launch_bounds__(256)
void k_cast(const float* __restrict__ x, __hip_bfloat16* __restrict__ o) {
  long i = ((long)blockIdx.x * 256 + threadIdx.x) * 8;
  float4 a = *(const float4*)&x[i];
  float4 b = *(const float4*)&x[i + 4];
  union { bf8 v; unsigned short h[8]; } u;
  u.h[0] = f2bf(a.x); u.h[1] = f2bf(a.y); u.h[2] = f2bf(a.z); u.h[3] = f2bf(a.w);
  u.h[4] = f2bf(b.x); u.h[5] = f2bf(b.y); u.h[6] = f2bf(b.z); u.h[7] = f2bf(b.w);
  *(bf8*)&o[i] = u.v;
}

// ---------------- Weff = W + B@A, concat [2304][768] bf16, + bias concat ----------------
__global__ __launch_bounds__(256)
void k_fold3(const float* __restrict__ W0, const float* __restrict__ A0, const float* __restrict__ B0,
             const float* __restrict__ W1, const float* __restrict__ A1, const float* __restrict__ B1,
             const float* __restrict__ W2, const float* __restrict__ A2, const float* __restrict__ B2,
             const float* __restrict__ bq, const float* __restrict__ bk, const float* __restrict__ bv,
             __hip_bfloat16* __restrict__ out, float* __restrict__ bcat) {
  int idx = blockIdx.x * 256 + threadIdx.x;
  if (idx < 2304)
    bcat[idx] = (idx < 768) ? bq[idx] : (idx < 1536) ? bk[idx - 768] : bv[idx - 1536];
  int t = idx / 589824, j = idx - t * 589824;
  const float* W = (t == 0) ? W0 : (t == 1) ? W1 : W2;
  const float* A = (t == 0) ? A0 : (t == 1) ? A1 : A2;
  const float* Bl = (t == 0) ? B0 : (t == 1) ? B1 : B2;
  int d = j % 768, o = j / 768;
  float acc = W[j];
  #pragma unroll
  for (int r = 0; r < 32; ++r) acc += Bl[o * 32 + r] * A[r * 768 + d];
  out[idx] = __float2bfloat16(acc);
}

// ---------------- 128x128x64 8-wave N-marching GEMM ----------------
// Out[m][n] = sum_k A[m][k] * B[n][k]
// MODE 0: PV   (A=P' ld4096, B=Vt ld8192 +z*4096, fp32 out / lsum)    MARCH=1
// MODE 1: scores (A=Q ld1536, B=A+768; P'=exp(acc*scale) + atomic lsum) MARCH=4
// MODE 3: proj (col<1536 -> bf16 [8192][1536] +bias; else Vt +bias)    MARCH=2
// Steps s = 0..NT*MARCH-1 flattened over (n-tile j = s/NT, k-step s%NT).
// Step parity = LDS buffer. Iter = 2 steps = 4 phases; race-free stages:
//   P0(buf0): read af(mh0)+bv; stage A(s+1)->buf1  [buf1 A free since prev iter]
//   P1(buf0): read af(mh1);    stage B(s+2)->buf0  [buf0 B read only in P0]; vmcnt(2)
//   P2(buf1): read af(mh0)+bv; stage A(s+2)->buf0  [buf0 A free after P1]
//   P3(buf1): read af(mh1);    stage B(s+3)->buf1  [buf1 B read only in P2]; vmcnt(2)
// Clamped tail stages rewrite identical bytes (s2/s3 clamp to S-1) -> benign.
template<int MODE, int MARCH>
__global__ __launch_bounds__(512, 4)
void k_gm(const __hip_bfloat16* __restrict__ Ag, const __hip_bfloat16* __restrict__ Bg,
          const float* __restrict__ bias, void* __restrict__ Og, void* __restrict__ Og2,
          float* __restrict__ lsum, float scale)
{
  __shared__ short lds[32768];   // 64 KiB: [buf2][opA/B][2half][64x64 bf16]
  constexpr int NT = (MODE == 0) ? 64 : 12;
  constexpr int S = NT * MARCH;
  const int tid = threadIdx.x, w = tid >> 6, lane = tid & 63;
  const int wm = w >> 2, wn = w & 3;
  const int lnlo = lane & 15, lnhi = lane >> 4;

  // T1 XCD swizzle, N-fast tile mapping
  const int gy = gridDim.y;
  const int nwg = gridDim.x * gy;
  const int w0 = blockIdx.y * gridDim.x + blockIdx.x;
  const int wid = (w0 & 7) * (nwg >> 3) + (w0 >> 3);
  const long M0 = (long)(wid / gy) * 128;
  const long NG0 = (long)(wid % gy) * (128 * MARCH);

  const __hip_bfloat16 *A, *B; long lda, ldb;
  if constexpr (MODE == 0) {
    A = Ag + (long)blockIdx.z * 4096 * 4096; lda = 4096;
    B = Bg + (long)blockIdx.z * 4096;        ldb = 8192;
  } else if constexpr (MODE == 1) {
    A = Ag + (long)blockIdx.z * 4096 * 1536; B = A + 768; lda = 1536; ldb = 1536;
  } else {
    A = Ag; B = Bg; lda = 768; ldb = 768;
  }

  // staging: half-tile 64 rows x 64 k = 1 gload16/thread; T2 pre-swizzled source col
  const int srow = tid >> 3;                       // 0..63
  const int scol = (((tid & 7) ^ (srow & 7)) << 3);
  const __hip_bfloat16* pA[2] = { A + (M0 + srow) * lda + scol, A + (M0 + 64 + srow) * lda + scol };
  const __hip_bfloat16* pB[2] = { B + (NG0 + srow) * ldb + scol, B + (NG0 + 64 + srow) * ldb + scol };
  char* Lc = (char*)lds;
  const int wbyte = w * 1024;
  auto stage = [&](int op, int h, int s) {         // 1 gload16/thread
    char* dst = Lc + (s & 1) * 32768 + op * 16384 + h * 8192 + wbyte;  // wave-uniform
    long off;
    if (op == 0) off = (long)(s % NT) * 64;
    else         off = (long)(s / NT) * 128 * ldb + (long)(s % NT) * 64;
    gload16((op ? pB[h] : pA[h]) + off, dst);
  };
  auto rdA = [&](int row, int k, int d) -> bf8 {   // T2-swizzled LDS read
    const int sb = ((k << 6) + (lnhi << 4)) ^ ((row & 7) << 4);
    return *(const bf8*)(Lc + d * 32768 + row * 128 + sb);
  };
  auto rdB = [&](int row, int k, int d) -> bf8 {
    const int sb = ((k << 6) + (lnhi << 4)) ^ ((row & 7) << 4);
    return *(const bf8*)(Lc + d * 32768 + 16384 + row * 128 + sb);
  };

  f32x4 acc[4][2] = {};   // wave tile 64x32: [m-frag][n-frag]

  // per-n-tile epilogue (no LDS use -> overlaps with in-flight staging)
  auto dump = [&](int j) {
    #pragma unroll
    for (int mi = 0; mi < 4; ++mi) {
      const long row = M0 + wm * 64 + mi * 16 + lnhi * 4;
      if constexpr (MODE == 0) {
        float* Of = (float*)Og + (long)blockIdx.z * 4096 * 768;
        const float* lz = lsum + (long)blockIdx.z * 4096;
        float linv[4];
        #pragma unroll
        for (int r = 0; r < 4; ++r) linv[r] = 1.0f / lz[row + r];
        #pragma unroll
        for (int ni = 0; ni < 2; ++ni) {
          const long col = NG0 + wn * 32 + ni * 16 + lnlo;
          #pragma unroll
          for (int r = 0; r < 4; ++r) Of[(row + r) * 768 + col] = acc[mi][ni][r] * linv[r];
        }
      } else if constexpr (MODE == 1) {
        __hip_bfloat16* Ob = (__hip_bfloat16*)Og + (long)blockIdx.z * 4096 * 4096;
        float* lz = lsum + (long)blockIdx.z * 4096;
        float rs[4] = {0.f, 0.f, 0.f, 0.f};
        #pragma unroll
        for (int ni = 0; ni < 2; ++ni) {
          const long col = NG0 + (long)j * 128 + wn * 32 + ni * 16 + lnlo;
          #pragma unroll
          for (int r = 0; r < 4; ++r) {
            const float e = __expf(fminf(acc[mi][ni][r] * scale, 70.0f));
            rs[r] += e;
            *(unsigned short*)&Ob[(row + r) * 4096 + col] = f2bf(e);
          }
        }
        #pragma unroll
        for (int r = 0; r < 4; ++r) {
          float v = rs[r];
          v += __shfl_xor(v, 1); v += __shfl_xor(v, 2);
          v += __shfl_xor(v, 4); v += __shfl_xor(v, 8);
          if (lnlo == 0) atomicAdd(&lz[row + r], v);
        }
      } else {
        #pragma unroll
        for (int ni = 0; ni < 2; ++ni) {
          const long col = NG0 + (long)j * 128 + wn * 32 + ni * 16 + lnlo;
          const float bvl = bias[col];
          if (col < 1536) {
            __hip_bfloat16* O = (__hip_bfloat16*)Og;
            #pragma unroll
            for (int r = 0; r < 4; ++r)
              *(unsigned short*)&O[(row + r) * 1536 + col] = f2bf(acc[mi][ni][r] + bvl);
          } else {
            __hip_bfloat16* O2 = (__hip_bfloat16*)Og2;
            bf4 v;
            #pragma unroll
            for (int r = 0; r < 4; ++r) v[r] = (short)f2bf(acc[mi][ni][r] + bvl);
            *(bf4*)&O2[(col - 1536) * 8192 + row] = v;
          }
        }
      }
    }
    #pragma unroll
    for (int mi = 0; mi < 4; ++mi)
      #pragma unroll
      for (int ni = 0; ni < 2; ++ni) acc[mi][ni] = (f32x4){0.f, 0.f, 0.f, 0.f};
  };

  // prologue: B(0),A(0),B(1) -> vmcnt(2) retires tile0
  stage(1,0,0); stage(1,1,0); stage(0,0,0); stage(0,1,0);
  stage(1,0,1); stage(1,1,1);
  asm volatile("s_waitcnt vmcnt(2)" ::: "memory");
  __builtin_amdgcn_s_barrier();
  asm volatile("" ::: "memory");

  bf8 af[2][2], bv[2][2];
  for (int s = 0; s < S; s += 2) {
    if (MARCH > 1 && s > 0 && (s % NT) == 0) dump(s / NT - 1);
    const int s1 = s + 1;
    const int s2 = (s + 2 < S) ? s + 2 : S - 1;   // clamp: rewrites identical bytes
    const int s3 = (s + 3 < S) ? s + 3 : S - 1;

    // ---- P0 (buf0, m-half 0) ----
    #pragma unroll
    for (int m = 0; m < 2; ++m)
      #pragma unroll
      for (int k = 0; k < 2; ++k) af[m][k] = rdA(wm * 64 + m * 16 + lnlo, k, 0);
    #pragma unroll
    for (int n = 0; n < 2; ++n)
      #pragma unroll
      for (int k = 0; k < 2; ++k) bv[n][k] = rdB(wn * 32 + n * 16 + lnlo, k, 0);
    stage(0,0,s1); stage(0,1,s1);
    asm volatile("" ::: "memory");
    __builtin_amdgcn_s_barrier();
    __builtin_amdgcn_s_setprio(1);
    #pragma unroll
    for (int m = 0; m < 2; ++m)
      #pragma unroll
      for (int n = 0; n < 2; ++n) {
        acc[m][n] = __builtin_amdgcn_mfma_f32_16x16x32_bf16(af[m][0], bv[n][0], acc[m][n], 0,0,0);
        acc[m][n] = __builtin_amdgcn_mfma_f32_16x16x32_bf16(af[m][1], bv[n][1], acc[m][n], 0,0,0);
      }
    __builtin_amdgcn_s_setprio(0);
    __builtin_amdgcn_s_barrier();
    asm volatile("" ::: "memory");

    // ---- P1 (buf0, m-half 1) ----
    #pragma unroll
    for (int m = 0; m < 2; ++m)
      #pragma unroll
      for (int k = 0; k < 2; ++k) af[m][k] = rdA(wm * 64 + 32 + m * 16 + lnlo, k, 0);
    stage(1,0,s2); stage(1,1,s2);
    asm volatile("" ::: "memory");
    __builtin_amdgcn_s_barrier();
    __builtin_amdgcn_s_setprio(1);
    #pragma unroll
    for (int m = 0; m < 2; ++m)
      #pragma unroll
      for (int n = 0; n < 2; ++n) {
        acc[2+m][n] = __builtin_amdgcn_mfma_f32_16x16x32_bf16(af[m][0], bv[n][0], acc[2+m][n], 0,0,0);
        acc[2+m][n] = __builtin_amdgcn_mfma_f32_16x16x32_bf16(af[m][1], bv[n][1], acc[2+m][n], 0,0,0);
      }
    __builtin_amdgcn_s_setprio(0);
    asm volatile("s_waitcnt vmcnt(2)" ::: "memory");   // A(s+1),B(s+1) landed
    __builtin_amdgcn_s_barrier();
    asm volatile("" ::: "memory");

    // ---- P2 (buf1, m-half 0) ----
    #pragma unroll
    for (int m = 0; m < 2; ++m)
      #pragma unroll
      for (int k = 0; k < 2; ++k) af[m][k] = rdA(wm * 64 + m * 16 + lnlo, k, 1);
    #pragma unroll
    for (int n = 0; n < 2; ++n)
      #pragma unroll
      for (int k = 0; k < 2; ++k) bv[n][k] = rdB(wn * 32 + n * 16 + lnlo, k, 1);
    stage(0,0,s2); stage(0,1,s2);
    asm volatile("" ::: "memory");
    __builtin_amdgcn_s_barrier();
    __builtin_amdgcn_s_setprio(1);
    #pragma unroll
    for (int m = 0; m < 2; ++m)
      #pragma unroll
      for (int n = 0; n < 2; ++n) {
        acc[m][n] = __builtin_amdgcn_mfma_f32_16x16x32_bf16(af[m][0], bv[n][0], acc[m][n], 0,0,0);
        acc[m][n] = __builtin_amdgcn_mfma_f32_16x16x32_bf16(af[m][1], bv[n][1], acc[m][n], 0,0,0);
      }
    __builtin_amdgcn_s_setprio(0);
    __builtin_amdgcn_s_barrier();
    asm volatile("" ::: "memory");

    // ---- P3 (buf1, m-half 1) ----
    #pragma unroll
    for (int m = 0; m < 2; ++m)
      #pragma unroll
      for (int k = 0; k < 2; ++k) af[m][k] = rdA(wm * 64 + 32 + m * 16 + lnlo, k, 1);
    stage(1,0,s3); stage(1,1,s3);
    asm volatile("" ::: "memory");
    __builtin_amdgcn_s_barrier();
    __builtin_amdgcn_s_setprio(1);
    #pragma unroll
    for (int m = 0; m < 2; ++m)
      #pragma unroll
      for (int n = 0; n < 2; ++n) {
        acc[2+m][n] = __builtin_amdgcn_mfma_f32_16x16x32_bf16(af[m][0], bv[n][0], acc[2+m][n], 0,0,0);
        acc[2+m][n] = __builtin_amdgcn_mfma_f32_16x16x32_bf16(af[m][1], bv[n][1], acc[2+m][n], 0,0,0);
      }
    __builtin_amdgcn_s_setprio(0);
    asm volatile("s_waitcnt vmcnt(2)" ::: "memory");   // A(s+2),B(s+2) landed
    __builtin_amdgcn_s_barrier();
    asm volatile("" ::: "memory");
  }

  dump(MARCH - 1);
}

extern "C" void kernel_launch(void* const* d_in, const int* in_sizes, int n_in,
                              void* d_out, int out_size, void* d_ws, size_t ws_size,
                              hipStream_t stream) {
  const float* x  = (const float*)d_in[0];
  const float* Wq = (const float*)d_in[1]; const float* bq = (const float*)d_in[2];
  const float* Wk = (const float*)d_in[3]; const float* bk = (const float*)d_in[4];
  const float* Wv = (const float*)d_in[5]; const float* bv = (const float*)d_in[6];
  const float* Aq = (const float*)d_in[7]; const float* Bq = (const float*)d_in[8];
  const float* Ak = (const float*)d_in[9]; const float* Bk = (const float*)d_in[10];
  const float* Av = (const float*)d_in[11]; const float* Bv = (const float*)d_in[12];

  // ws layout (bf16 elems), ~121 MB
  __hip_bfloat16* Xb   = (__hip_bfloat16*)d_ws;        // [8192][768]
  __hip_bfloat16* WeA  = Xb  + 6291456;                // [2304][768]
  __hip_bfloat16* QKb  = WeA + 1769472;                // [8192][1536] (Q 0-767, K 768-1535)
  __hip_bfloat16* Vt   = QKb + 12582912;               // [768][8192]
  __hip_bfloat16* Pb   = Vt  + 6291456;                // [2][4096][4096] unnormalized exp
  float*          bcat = (float*)(Pb + 33554432);      // [2304]
  float*          lsum = bcat + 2304;                  // [2][4096] row sums
  float* out = (float*)d_out;

  k_cast<<<3072, 256, 0, stream>>>(x, Xb);
  k_fold3<<<6912, 256, 0, stream>>>(Wq, Aq, Bq, Wk, Ak, Bk, Wv, Av, Bv,
                                    bq, bk, bv, WeA, bcat);
  hipMemsetAsync(lsum, 0, 8192 * sizeof(float), stream);

  // projections: M=8192, N=2304, K=768 (march 2 n-tiles/block)
  k_gm<3, 2><<<dim3(64, 9, 1), 512, 0, stream>>>(Xb, WeA, bcat, QKb, Vt, nullptr, 1.0f);
  // scores + exp + rowsum: per batch M=N=4096, K=768 (march 4)
  const float sc = 0.036084391824351615f;
  k_gm<1, 4><<<dim3(32, 8, 2), 512, 0, stream>>>(QKb, nullptr, nullptr, Pb, nullptr, lsum, sc);
  // PV: per batch M=4096, N=768, K=4096 (march 1); epilogue normalizes by lsum
  k_gm<0, 1><<<dim3(32, 6, 2), 512, 0, stream>>>(Pb, Vt, nullptr, out, nullptr, lsum, 1.0f);
}